// Round 9
// baseline (34.880 us; speedup 1.0000x reference)
//
#include <hip/hip_runtime.h>
#include <math.h>

#define EPS_T 1e-4f
#define BIG 1e10f
#define NRM_EPS 1e-12f

// ---- inline-asm: 1 sphere per body, scalar math, 5-deep LDS prefetch ring --
// Work regs v32..v36; buffers v[40:43] v[44:47] v[48:51] v[52:55] v[56:59].
// Table: tab[s] = float4(cx, cy, cz, -w), w = |c|^2 - r^2.
// Bit-exact rounding forms of the R6-passed kernel:
//   doc = fma(dx,cx, fma(dy,cy, dz*cz));  ooc likewise
//   bm  = doc + (-od)
//   ncv = fma(ooc, 2.0, -oo) + (-w)
//   dsc = fma(bm, bm, ncv)
//   t   = bm - v_sqrt(dsc);  dsc<0 -> NaN -> ordered cmps false -> rejected
// HAZARD NOTE: trans op (v_sqrt) result must not be consumed by the next
// instruction — R8 failed with a 0-gap; here the prefetch (ds_read + v_add,
// 2 instrs) sits between sqrt and its consumer; drain bodies use s_nop 1.
// Single sequential select chain (s=0..127), strict < : exact jnp.argmin
// first-occurrence semantics.
#define PFB(R) \
  "ds_read_b128 " R ", %[lda]\n\t" \
  "v_add_u32 %[lda], 16, %[lda]\n\t"

#define SB(W, X, Y, Z, WN, GAP) \
  W \
  "v_mul_f32 v32, %[dz], " Z "\n\t" \
  "v_mul_f32 v33, %[oz], " Z "\n\t" \
  "v_fma_f32 v32, %[dy], " Y ", v32\n\t" \
  "v_fma_f32 v33, %[oy], " Y ", v33\n\t" \
  "v_fma_f32 v32, %[dx], " X ", v32\n\t" \
  "v_fma_f32 v33, %[ox], " X ", v33\n\t" \
  "v_add_f32 v34, v32, %[nod]\n\t" \
  "v_fma_f32 v35, v33, 2.0, %[noo]\n\t" \
  "v_add_f32 v35, v35, " WN "\n\t" \
  "v_fma_f32 v35, v34, v34, v35\n\t" \
  "v_sqrt_f32 v36, v35\n\t" \
  GAP \
  "v_sub_f32 v36, v34, v36\n\t" \
  "v_cmp_lt_f32 vcc, %[eps], v36\n\t" \
  "v_cmp_gt_f32 s[20:21], %[tmin], v36\n\t" \
  "s_and_b64 vcc, vcc, s[20:21]\n\t" \
  "v_cndmask_b32 %[tmin], %[tmin], v36, vcc\n\t" \
  "v_cndmask_b32 %[sidx], %[sidx], %[vj], vcc\n\t" \
  "v_add_u32 %[vj], 1, %[vj]\n\t"

#define W4 "s_waitcnt lgkmcnt(4)\n\t"

__global__ __launch_bounds__(256) void illum_kernel(
    const float* __restrict__ ray_o,
    const float* __restrict__ ray_d,
    const float* __restrict__ centers,
    const float* __restrict__ radii,
    const float* __restrict__ light_pos,
    const int*   __restrict__ light_idx,
    float* __restrict__ out,   // [N*3] results, then [N] active(0/1)
    int N)
{
    __shared__ float4 tab[128];   // tab[s] = (cx, cy, cz, -w)

    const int tid = threadIdx.x;
    if (tid < 128) {
        float cx = centers[3 * tid + 0];
        float cy = centers[3 * tid + 1];
        float cz = centers[3 * tid + 2];
        float r  = radii[tid];
        float w  = cx * cx + cy * cy + cz * cz - r * r;
        tab[tid] = make_float4(cx, cy, cz, -w);
    }
    __syncthreads();

    const int i = blockIdx.x * blockDim.x + tid;
    if (i >= N) return;

    float ox = ray_o[3 * i + 0], oy = ray_o[3 * i + 1], oz = ray_o[3 * i + 2];
    float dx = ray_d[3 * i + 0], dy = ray_d[3 * i + 1], dz = ray_d[3 * i + 2];

    // d = normalize(ray_d), precise (once per ray)
    float dn  = sqrtf(dx * dx + dy * dy + dz * dz);
    float din = 1.0f / fmaxf(dn, NRM_EPS);
    dx *= din; dy *= din; dz *= din;

    const float od = ox * dx + oy * dy + oz * dz;
    const float oo = ox * ox + oy * oy + oz * oz;
    const float nod = -od;
    const float noo = -oo;

    float tmin = BIG;
    int sidx = 0, vj = 0;
    unsigned lda = (unsigned)(size_t)&tab[0];

    asm volatile(
        "s_waitcnt lgkmcnt(0)\n\t"
        PFB("v[40:43]") PFB("v[44:47]") PFB("v[48:51]") PFB("v[52:55]") PFB("v[56:59]")
        ".rept 24\n\t"                       // spheres 0..119 (24 x 5 bodies)
        SB(W4, "v40","v41","v42","v43", PFB("v[40:43]"))
        SB(W4, "v44","v45","v46","v47", PFB("v[44:47]"))
        SB(W4, "v48","v49","v50","v51", PFB("v[48:51]"))
        SB(W4, "v52","v53","v54","v55", PFB("v[52:55]"))
        SB(W4, "v56","v57","v58","v59", PFB("v[56:59]"))
        ".endr\n\t"
        // spheres 120..122, still prefetching 125..127
        SB(W4, "v40","v41","v42","v43", PFB("v[40:43]"))
        SB(W4, "v44","v45","v46","v47", PFB("v[44:47]"))
        SB(W4, "v48","v49","v50","v51", PFB("v[48:51]"))
        // tail: spheres 123..127, draining waits; s_nop 1 covers trans hazard
        SB("s_waitcnt lgkmcnt(4)\n\t", "v52","v53","v54","v55", "s_nop 1\n\t")
        SB("s_waitcnt lgkmcnt(3)\n\t", "v56","v57","v58","v59", "s_nop 1\n\t")
        SB("s_waitcnt lgkmcnt(2)\n\t", "v40","v41","v42","v43", "s_nop 1\n\t")
        SB("s_waitcnt lgkmcnt(1)\n\t", "v44","v45","v46","v47", "s_nop 1\n\t")
        SB("s_waitcnt lgkmcnt(0)\n\t", "v48","v49","v50","v51", "s_nop 1\n\t")
        : [tmin]"+v"(tmin), [sidx]"+v"(sidx), [vj]"+v"(vj), [lda]"+v"(lda)
        : [dx]"v"(dx), [dy]"v"(dy), [dz]"v"(dz),
          [ox]"v"(ox), [oy]"v"(oy), [oz]"v"(oz),
          [nod]"v"(nod), [noo]"v"(noo),
          [eps]"s"(1e-4f)
        : "v32","v33","v34","v35","v36",
          "v40","v41","v42","v43","v44","v45","v46","v47",
          "v48","v49","v50","v51","v52","v53","v54","v55",
          "v56","v57","v58","v59",
          "s20","s21","vcc","scc","memory");

    const bool active = (tmin < BIG);

    // hit point
    float px = fmaf(tmin, dx, ox);
    float py = fmaf(tmin, dy, oy);
    float pz = fmaf(tmin, dz, oz);

    // surface normal (center from LDS table)
    float4 cb = tab[sidx];
    float nx = px - cb.x, ny = py - cb.y, nz = pz - cb.z;
    float nn  = sqrtf(nx * nx + ny * ny + nz * nz);
    float nin = 1.0f / fmaxf(nn, NRM_EPS);
    nx *= nin; ny *= nin; nz *= nin;

    // direction to sampled light
    int li = light_idx[i];
    float dsx = light_pos[3 * li + 0] - px;
    float dsy = light_pos[3 * li + 1] - py;
    float dsz = light_pos[3 * li + 2] - pz;

    // Duff et al. branchless orthonormal frame; local = (d.s, d.t, d.n)
    float sgn = (nz >= 0.0f) ? 1.0f : -1.0f;
    float a   = -1.0f / (sgn + nz);
    float bb  = nx * ny * a;
    float sx = 1.0f + sgn * nx * nx * a, sy = sgn * bb,          sz = -sgn * nx;
    float tx = bb,                       ty = sgn + ny * ny * a, tz = -ny;

    float l0 = dsx * sx + dsy * sy + dsz * sz;
    float l1 = dsx * tx + dsy * ty + dsz * tz;
    float l2 = dsx * nx + dsy * ny + dsz * nz;
    float ln  = sqrtf(l0 * l0 + l1 * l1 + l2 * l2);
    float lin = 1.0f / fmaxf(ln, NRM_EPS);

    float r0 = active ? (l0 * lin + 1.0f) * 0.5f : 0.0f;
    float r1 = active ? (l1 * lin + 1.0f) * 0.5f : 0.0f;
    float r2 = active ? (l2 * lin + 1.0f) * 0.5f : 0.0f;

    out[3 * i + 0] = (1.0f + r0) * 0.5f;
    out[3 * i + 1] = (1.0f + r1) * 0.5f;
    out[3 * i + 2] = (1.0f + r2) * 0.5f;
    out[(size_t)3 * N + i] = active ? 1.0f : 0.0f;
}

extern "C" void kernel_launch(void* const* d_in, const int* in_sizes, int n_in,
                              void* d_out, int out_size, void* d_ws, size_t ws_size,
                              hipStream_t stream) {
    const float* ray_o     = (const float*)d_in[0];
    const float* ray_d     = (const float*)d_in[1];
    const float* centers   = (const float*)d_in[2];
    const float* radii     = (const float*)d_in[3];
    const float* light_pos = (const float*)d_in[4];
    const int*   light_idx = (const int*)d_in[5];
    float* out = (float*)d_out;

    const int N = in_sizes[0] / 3;   // S fixed at 128

    const int block = 256;
    const int grid  = (N + block - 1) / block;
    illum_kernel<<<grid, block, 0, stream>>>(ray_o, ray_d, centers, radii,
                                             light_pos, light_idx, out, N);
}